// Round 9
// baseline (138.932 us; speedup 1.0000x reference)
//
#include <hip/hip_runtime.h>
#include <hip/hip_bf16.h>
#include <math.h>

typedef __attribute__((ext_vector_type(8))) short bf16x8;
typedef __attribute__((ext_vector_type(4))) float f32x4;

#define B_   16
#define C_   64
#define C1_  8
#define C2_  32
#define HW_  4096
#define M_   1024
#define LOG2E 1.4426950408889634f
#define MFMA_BF16 __builtin_amdgcn_mfma_f32_16x16x32_bf16

__device__ __forceinline__ unsigned short f2bf(float f) {
  union { float f; unsigned u; } v; v.f = f;
  unsigned r = (v.u + 0x7fffu + ((v.u >> 16) & 1u)) >> 16;
  return (unsigned short)r;
}
__device__ __forceinline__ float bf2f(unsigned short h) {
  union { unsigned u; float f; } v; v.u = ((unsigned)h) << 16;
  return v.f;
}

// phi slot permutation within each 32-key group (bank-conflict-free LDS
// reads in k_attn given 48-B row stride): slot(k) = ((k&7)<<2) | (k>>3)
__device__ __forceinline__ int slot32(int m) {
  return (m & 0xFFE0) | (((m & 7) << 2) | ((m >> 3) & 3));
}

// ---------------------------------------------------------------------------
// K1 v9 (TRANSPOSED): lane = output channel (o<8 -> phi, 8<=o<40 -> g),
// weights held in VGPRs (vector-loaded once), pixel loop wave-uniform so
// x reads compile to s_load_dword (scalar pipe, prefetchable, stride
// 16 KB fits the 21-bit imm). Pooling is in-register fmax across the
// 4-corner loop. No LDS, no barriers, no shuffles.
// Grid: 512 blocks x 256 thr = 2048 waves; wave handles 8 pooled m.
// ---------------------------------------------------------------------------
__global__ __launch_bounds__(256, 4)
void k_pre(const float* __restrict__ x,
           const float* __restrict__ w_phi, const float* __restrict__ b_phi,
           const float* __restrict__ w_g,   const float* __restrict__ b_g,
           unsigned short* __restrict__ phi_s,
           unsigned short* __restrict__ g_t) {
  int tid  = threadIdx.x;
  int lane = tid & 63;
  int wv   = tid >> 6;
  int wave_id = blockIdx.x * 4 + wv;       // 0..2047
  int o  = lane;
  int go = (o >= 8) ? ((o - 8 > 31) ? 31 : (o - 8)) : 0;

  // per-lane weight row: 64 floats in VGPRs (16 float4 loads, once)
  const float* wrow = (o < 8) ? (w_phi + o * C_) : (w_g + go * C_);
  float w[64];
  #pragma unroll
  for (int v = 0; v < 16; ++v) {
    float4 t = ((const float4*)wrow)[v];
    w[4*v+0] = t.x; w[4*v+1] = t.y; w[4*v+2] = t.z; w[4*v+3] = t.w;
  }
  float bias = (o < 8) ? b_phi[o] : b_g[go];

  #pragma unroll
  for (int j = 0; j < 8; ++j) {
    int pm = wave_id * 8 + j;              // pooled id, wave-uniform
    int b = pm >> 10;
    int m = pm & 1023;
    float pooled = -3.4e38f;
    #pragma unroll
    for (int pix = 0; pix < 4; ++pix) {
      int n = (2*(m >> 5) + (pix >> 1)) * 64 + 2*(m & 31) + (pix & 1);
      int xoff = __builtin_amdgcn_readfirstlane(b * C_ * HW_ + n);
      const float* xp = x + xoff;
      float cur = 0.f;
      #pragma unroll
      for (int c = 0; c < C_; ++c) cur += xp[(size_t)c * HW_] * w[c];
      pooled = fmaxf(pooled, cur);
    }
    pooled += bias;

    if (o < 8) {
      // scrambled slot f = o*16 + b -> buffer batch f>>3, channel f&7;
      // m written at its permuted 32-group slot
      int f = o * 16 + b;
      unsigned short hi = f2bf(pooled);
      unsigned short* pr = phi_s + ((size_t)(f >> 3) * M_ + slot32(m)) * 16;
      pr[f & 7]       = hi;
      pr[8 + (f & 7)] = f2bf(pooled - bf2f(hi));
    } else if (o < 40) {
      g_t[((size_t)b * C2_ + (o - 8)) * M_ + m] = f2bf(pooled);
    }
  }
}

// ---------------------------------------------------------------------------
// K2 v9: R6 structure (512 thr, 8 waves = 4 row-groups x 2 key-halves,
// 2 staging phases) with phi LDS rows at 48-B stride + the slot32 key
// permutation (already applied in global phi_s) -> QK A-frag ds_reads are
// bank-conflict-free (was structural 4-way, 1.49M conflict cycles in R7).
// ---------------------------------------------------------------------------
__global__ __launch_bounds__(512, 4)
void k_attn(const float* __restrict__ x,
            const float* __restrict__ w_delta,
            const float* __restrict__ b_delta,
            const unsigned short* __restrict__ phi_s,
            const unsigned short* __restrict__ g_t,
            const float* __restrict__ w_last,
            const float* __restrict__ b_last,
            const float* __restrict__ gamma,
            float* __restrict__ out) {
  __shared__ __align__(16) unsigned char lds_raw[57856];
  __shared__ __align__(8)  unsigned short delta_lds[128*16];    // [row][dh8 dl8]
  unsigned short* phi_lds = (unsigned short*)lds_raw;           // 512*24*2 = 24576 B
  unsigned short* g_lds   = (unsigned short*)(lds_raw + 24576); // 32*520*2 = 33280 B
  float* o_sh = (float*)lds_raw;                                // 128*33*4 = 16896 B (reuse)
  float* cmb  = (float*)(lds_raw + 16896);                      // 128*34*4 = 17408 B (reuse)

  int tid  = threadIdx.x;
  int lane = tid & 63;
  int wv   = tid >> 6;             // 0..7
  int rg   = wv & 3;               // row-group: rows rg*32 .. rg*32+31
  int kh   = wv >> 2;              // key half within phase (256 keys)
  int r    = lane & 15;
  int q    = lane >> 4;
  int bx = blockIdx.x;             // 0..511
  int b  = bx >> 5;
  int n0 = (bx & 31) * 128;

  // ---- delta preamble: 4 threads/row x 2 channels, scalar weights
  {
    int row  = tid & 127;
    int cp2  = __builtin_amdgcn_readfirstlane(tid >> 7);  // 0..3, wave-uniform
    const float* wd0 = w_delta + (2*cp2)   * C_;
    const float* wd1 = w_delta + (2*cp2+1) * C_;
    const float* xr  = x + (size_t)b*C_*HW_ + n0 + row;
    float a0 = 0.f, a1 = 0.f;
    #pragma unroll
    for (int c = 0; c < C_; ++c) {
      float v = xr[(size_t)c * HW_];
      a0 += v * wd0[c];
      a1 += v * wd1[c];
    }
    a0 = (a0 + b_delta[2*cp2])   * LOG2E;
    a1 = (a1 + b_delta[2*cp2+1]) * LOG2E;
    unsigned short h0 = f2bf(a0), h1 = f2bf(a1);
    unsigned short l0 = f2bf(a0 - bf2f(h0)), l1 = f2bf(a1 - bf2f(h1));
    *(unsigned*)(delta_lds + row*16 + 2*cp2)     = (unsigned)h0 | ((unsigned)h1 << 16);
    *(unsigned*)(delta_lds + row*16 + 8 + 2*cp2) = (unsigned)l0 | ((unsigned)l1 << 16);
  }
  __syncthreads();

  // 2 Q-tiles per wave; B-frag half selected by q&1
  bf16x8 df[2];
  #pragma unroll
  for (int t = 0; t < 2; ++t)
    df[t] = *(const bf16x8*)(delta_lds + (rg*32 + t*16 + r)*16 + (q & 1)*8);

  int phi_off = (q >> 1) * 8;               // [ph ph pl pl] across k
  // permuted-slot indices for logical key0=(r>>2)*8+(r&3), key1=key0+4
  int ks0 = ((r & 3) << 2) | (r >> 2);
  int ks1 = ks0 + 16;

  bf16x8 ones;
  #pragma unroll
  for (int i = 0; i < 8; ++i) ones[i] = (short)0x3F80;  // bf16 1.0

  f32x4 acc[2][2];                 // [tile][c-half]
  f32x4 den[2];
  f32x4 zero = {0,0,0,0};
  #pragma unroll
  for (int t = 0; t < 2; ++t) { acc[t][0] = zero; acc[t][1] = zero; den[t] = zero; }

  for (int p = 0; p < 2; ++p) {
    if (p) __syncthreads();                 // everyone done reading phase 0
    // ---- stage phi half: thread t copies row t (32 B) into 48-B-stride row
    {
      const uint4* src = (const uint4*)(phi_s + ((size_t)b*M_ + p*512 + tid)*16);
      unsigned short* dst = phi_lds + tid*24;
      ((uint4*)dst)[0] = src[0];
      *(uint4*)(dst + 8) = src[1];
      // ---- stage g half: 2048 16B units into padded rows
      #pragma unroll
      for (int u = 0; u < 4; ++u) {
        int uu = tid + u*512;
        int c2 = uu >> 6, pos = uu & 63;
        *(uint4*)(g_lds + c2*520 + pos*8) =
            *(const uint4*)(g_t + ((size_t)b*C2_ + c2)*M_ + p*512 + pos*8);
      }
    }
    __syncthreads();

    // ---- K-loop on LDS only (no barriers inside)
    #pragma unroll 2
    for (int kc = 0; kc < 256; kc += 32) {
      int kl = kh*256 + kc;        // phase-local key base (multiple of 32)
      bf16x8 aphi0 = *(const bf16x8*)(phi_lds + (size_t)(kl + ks0)*24 + phi_off);
      bf16x8 aphi1 = *(const bf16x8*)(phi_lds + (size_t)(kl + ks1)*24 + phi_off);
      bf16x8 bg0   = *(const bf16x8*)(g_lds + r*520        + kl + q*8);
      bf16x8 bg1   = *(const bf16x8*)(g_lds + (16 + r)*520 + kl + q*8);

      #pragma unroll
      for (int t = 0; t < 2; ++t) {
        f32x4 s0 = MFMA_BF16(aphi0, df[t], zero, 0, 0, 0);
        f32x4 s1 = MFMA_BF16(aphi1, df[t], zero, 0, 0, 0);
        union { bf16x8 v; __hip_bfloat162 h[4]; } e;
        e.h[0] = __float22bfloat162_rn(make_float2(__builtin_amdgcn_exp2f(s0[0]),
                                                   __builtin_amdgcn_exp2f(s0[1])));
        e.h[1] = __float22bfloat162_rn(make_float2(__builtin_amdgcn_exp2f(s0[2]),
                                                   __builtin_amdgcn_exp2f(s0[3])));
        e.h[2] = __float22bfloat162_rn(make_float2(__builtin_amdgcn_exp2f(s1[0]),
                                                   __builtin_amdgcn_exp2f(s1[1])));
        e.h[3] = __float22bfloat162_rn(make_float2(__builtin_amdgcn_exp2f(s1[2]),
                                                   __builtin_amdgcn_exp2f(s1[3])));
        acc[t][0] = MFMA_BF16(e.v, bg0, acc[t][0], 0, 0, 0);
        acc[t][1] = MFMA_BF16(e.v, bg1, acc[t][1], 0, 0, 0);
        den[t]    = MFMA_BF16(e.v, ones, den[t], 0, 0, 0);
      }
    }
  }

  // ---- combine the two key-halves (cmb reuses staging LDS)
  __syncthreads();                          // all waves done reading g/phi LDS
  if (kh == 1) {
    #pragma unroll
    for (int t = 0; t < 2; ++t) {
      #pragma unroll
      for (int reg = 0; reg < 4; ++reg) {
        int row = rg*32 + t*16 + q*4 + reg;
        cmb[row*34 + r]      = acc[t][0][reg];
        cmb[row*34 + 16 + r] = acc[t][1][reg];
        if (r == 0) cmb[row*34 + 32] = den[t][reg];
      }
    }
  }
  __syncthreads();
  if (kh == 0) {
    #pragma unroll
    for (int t = 0; t < 2; ++t) {
      #pragma unroll
      for (int reg = 0; reg < 4; ++reg) {
        int row = rg*32 + t*16 + q*4 + reg;
        float o0 = acc[t][0][reg] + cmb[row*34 + r];
        float o1 = acc[t][1][reg] + cmb[row*34 + 16 + r];
        float dn = den[t][reg]    + cmb[row*34 + 32];
        float iv = __builtin_amdgcn_rcpf(dn);
        o_sh[row*33 + r]      = o0 * iv;
        o_sh[row*33 + 16 + r] = o1 * iv;
      }
    }
  }
  __syncthreads();

  // ---- epilogue: out[b,co,n0+rr] = gamma*(w_last[co,:].O[rr,:]+b_last[co])+x
  int rr  = tid & 127;
  int wqu = __builtin_amdgcn_readfirstlane(tid >> 7);  // 0..3, uniform
  float o_reg[32];
  #pragma unroll
  for (int c = 0; c < 32; ++c) o_reg[c] = o_sh[rr*33 + c];
  float gm = gamma[0];
  for (int i = 0; i < 16; ++i) {
    int co = wqu*16 + i;                     // uniform -> s_load weights
    const float* wl = w_last + co*32;
    float a = b_last[co];
    #pragma unroll
    for (int c = 0; c < 32; ++c) a += wl[c] * o_reg[c];
    size_t oi = ((size_t)b*C_ + co)*HW_ + (size_t)(n0 + rr);
    out[oi] = gm * a + x[oi];
  }
}

// ---------------------------------------------------------------------------
extern "C" void kernel_launch(void* const* d_in, const int* in_sizes, int n_in,
                              void* d_out, int out_size, void* d_ws, size_t ws_size,
                              hipStream_t stream) {
  const float* x       = (const float*)d_in[0];
  const float* w_delta = (const float*)d_in[1];
  const float* b_delta = (const float*)d_in[2];
  const float* w_phi   = (const float*)d_in[3];
  const float* b_phi   = (const float*)d_in[4];
  const float* w_g     = (const float*)d_in[5];
  const float* b_g     = (const float*)d_in[6];
  const float* w_last  = (const float*)d_in[7];
  const float* b_last  = (const float*)d_in[8];
  const float* gamma   = (const float*)d_in[9];
  float* out = (float*)d_out;

  unsigned short* ws = (unsigned short*)d_ws;
  unsigned short* phi_s = ws;                          // 16*1024*16 = 0.5 MB
  unsigned short* g_t   = ws + (size_t)B_*M_*16;       // 16*32*1024 = 1 MB

  hipLaunchKernelGGL(k_pre, dim3(512), dim3(256), 0, stream,
                     x, w_phi, b_phi, w_g, b_g, phi_s, g_t);
  hipLaunchKernelGGL(k_attn, dim3(512), dim3(512), 0, stream,
                     x, w_delta, b_delta, phi_s, g_t, w_last, b_last, gamma, out);
}

// Round 10
// 115.876 us; speedup vs baseline: 1.1990x; 1.1990x over previous
//
#include <hip/hip_runtime.h>
#include <hip/hip_bf16.h>
#include <math.h>

typedef __attribute__((ext_vector_type(8))) short bf16x8;
typedef __attribute__((ext_vector_type(4))) float f32x4;

#define B_   16
#define C_   64
#define C1_  8
#define C2_  32
#define HW_  4096
#define M_   1024
#define LOG2E 1.4426950408889634f
#define MFMA_BF16 __builtin_amdgcn_mfma_f32_16x16x32_bf16

__device__ __forceinline__ unsigned short f2bf(float f) {
  union { float f; unsigned u; } v; v.f = f;
  unsigned r = (v.u + 0x7fffu + ((v.u >> 16) & 1u)) >> 16;
  return (unsigned short)r;
}
__device__ __forceinline__ float bf2f(unsigned short h) {
  union { unsigned u; float f; } v; v.u = ((unsigned)h) << 16;
  return v.f;
}

// ---------------------------------------------------------------------------
// K1: phi + g only -- EXACT R6 version (proven in the 114.7 config).
//   phi_s[b][m][16] : [ph(8) pl(8)] hi/lo split, batch/channel scrambled
//   g_t  [b][c2][m] : bf16 (transposed for PV B-frag reads)
// ---------------------------------------------------------------------------
__global__ __launch_bounds__(256, 4)
void k_pre(const float* __restrict__ x,
           const float* __restrict__ w_phi, const float* __restrict__ b_phi,
           const float* __restrict__ w_g,   const float* __restrict__ b_g,
           unsigned short* __restrict__ phi_s,
           unsigned short* __restrict__ g_t) {
  __shared__ float comb[2*64*41];
  int tid = threadIdx.x;

  int qt  = tid >> 6;              // channel quarter == wave index
  int sub = tid & 63;
  int id  = blockIdx.x * 64 + sub; // pixel id 0..65535
  int pix = id & 3;                // 2x2 corner (lane bits 0..1)
  int pm  = id >> 2;
  int b = pm >> 10;
  int m = pm & 1023;
  int py = 2*(m >> 5) + (pix >> 1);
  int px = 2*(m & 31) + (pix & 1);
  int n = py * 64 + px;

  int c0 = __builtin_amdgcn_readfirstlane(qt << 4);

  const float* xp = x + ((size_t)b*C_ + c0)*HW_ + n;
  float xv[16];
  #pragma unroll
  for (int i = 0; i < 16; ++i) xv[i] = xp[(size_t)i * HW_];

  float ap[8], ag[32];
  #pragma unroll
  for (int o = 0; o < 8; ++o) {
    const float* wp = w_phi + o*C_ + c0;     // uniform -> s_load
    float a = 0.f;
    #pragma unroll
    for (int i = 0; i < 16; ++i) a += xv[i]*wp[i];
    ap[o] = a;
  }
  #pragma unroll
  for (int o = 0; o < 32; ++o) {
    const float* wg = w_g + o*C_ + c0;       // uniform -> s_load
    float a = 0.f;
    #pragma unroll
    for (int i = 0; i < 16; ++i) a += xv[i]*wg[i];
    ag[o] = a;
  }

  if (qt == 1 || qt == 3) {
    float* cb = comb + (((qt >> 1)*64) + sub)*41;
    #pragma unroll
    for (int o = 0; o < 8; ++o) cb[o] = ap[o];
    #pragma unroll
    for (int o = 0; o < 32; ++o) cb[8+o] = ag[o];
  }
  __syncthreads();
  if (qt == 0 || qt == 2) {
    const float* cb = comb + (((qt >> 1)*64) + sub)*41;
    #pragma unroll
    for (int o = 0; o < 8; ++o) ap[o] += cb[o];
    #pragma unroll
    for (int o = 0; o < 32; ++o) ag[o] += cb[8+o];
  }
  __syncthreads();
  if (qt == 2) {
    float* cb = comb + sub*41;
    #pragma unroll
    for (int o = 0; o < 8; ++o) cb[o] = ap[o];
    #pragma unroll
    for (int o = 0; o < 32; ++o) cb[8+o] = ag[o];
  }
  __syncthreads();
  if (qt == 0) {
    const float* cb = comb + sub*41;
    #pragma unroll
    for (int o = 0; o < 8; ++o) ap[o] += cb[o];
    #pragma unroll
    for (int o = 0; o < 32; ++o) ag[o] += cb[8+o];

    #pragma unroll
    for (int o = 0; o < 8; ++o) {
      float v = ap[o];
      v = fmaxf(v, __shfl_xor(v, 1));
      v = fmaxf(v, __shfl_xor(v, 2));
      ap[o] = v;
    }
    #pragma unroll
    for (int o = 0; o < 32; ++o) {
      float v = ag[o];
      v = fmaxf(v, __shfl_xor(v, 1));
      v = fmaxf(v, __shfl_xor(v, 2));
      ag[o] = v;
    }

    if ((sub & 3) == 0) {
      #pragma unroll
      for (int cp = 0; cp < 8; ++cp) {
        int f = cp*16 + b;
        float v = ap[cp] + b_phi[cp];
        unsigned short hi = f2bf(v);
        unsigned short* pr = phi_s + ((size_t)(f >> 3)*M_ + m)*16;
        pr[f & 7]       = hi;
        pr[8 + (f & 7)] = f2bf(v - bf2f(hi));
      }
      #pragma unroll
      for (int o = 0; o < 32; ++o)
        g_t[((size_t)b*C2_ + o)*M_ + m] = f2bf(ag[o] + b_g[o]);
    }
  }
}

// ---------------------------------------------------------------------------
// K2 v10: R6 skeleton (512 thr, 512 blocks, 2 staging phases, 2 blocks/CU,
// 4 waves/SIMD) with t=4 Q-tiles/wave: 8 waves = 2 row-groups(64 rows) x
// 4 key-quarters. Each phi/g ds_read feeds 4 MFMA chains (was 2) -> LDS
// reads and per-chunk overhead halved, ILP doubled. 3-region combine.
// ---------------------------------------------------------------------------
__global__ __launch_bounds__(512, 4)
void k_attn(const float* __restrict__ x,
            const float* __restrict__ w_delta,
            const float* __restrict__ b_delta,
            const unsigned short* __restrict__ phi_s,
            const unsigned short* __restrict__ g_t,
            const float* __restrict__ w_last,
            const float* __restrict__ b_last,
            const float* __restrict__ gamma,
            float* __restrict__ out) {
  __shared__ __align__(16) unsigned char lds_raw[69120];
  __shared__ __align__(8)  unsigned short delta_lds[128*16];    // [row][dh8 dl8]
  unsigned short* phi_lds = (unsigned short*)lds_raw;           // 512*16*2 = 16384 B
  unsigned short* g_lds   = (unsigned short*)(lds_raw + 16384); // 32*520*2 = 33280 B
  float* o_sh = (float*)lds_raw;                                // 128*33*4 = 16896 B (reuse)
  float* cmb  = (float*)(lds_raw + 16896);                      // 3*128*34*4 = 52224 B (reuse)

  int tid  = threadIdx.x;
  int lane = tid & 63;
  int wv   = tid >> 6;             // 0..7
  int rg   = wv & 1;               // row-group: rows rg*64 .. rg*64+63
  int kh   = wv >> 1;              // key quarter within phase (128 keys)
  int r    = lane & 15;
  int q    = lane >> 4;
  int bx = blockIdx.x;             // 0..511
  int b  = bx >> 5;
  int n0 = (bx & 31) * 128;

  // ---- delta preamble: 4 threads/row x 2 channels, scalar weights (R6)
  {
    int row  = tid & 127;
    int cp2  = __builtin_amdgcn_readfirstlane(tid >> 7);  // 0..3, wave-uniform
    const float* wd0 = w_delta + (2*cp2)   * C_;
    const float* wd1 = w_delta + (2*cp2+1) * C_;
    const float* xr  = x + (size_t)b*C_*HW_ + n0 + row;
    float a0 = 0.f, a1 = 0.f;
    #pragma unroll
    for (int c = 0; c < C_; ++c) {
      float v = xr[(size_t)c * HW_];
      a0 += v * wd0[c];
      a1 += v * wd1[c];
    }
    a0 = (a0 + b_delta[2*cp2])   * LOG2E;
    a1 = (a1 + b_delta[2*cp2+1]) * LOG2E;
    unsigned short h0 = f2bf(a0), h1 = f2bf(a1);
    unsigned short l0 = f2bf(a0 - bf2f(h0)), l1 = f2bf(a1 - bf2f(h1));
    *(unsigned*)(delta_lds + row*16 + 2*cp2)     = (unsigned)h0 | ((unsigned)h1 << 16);
    *(unsigned*)(delta_lds + row*16 + 8 + 2*cp2) = (unsigned)l0 | ((unsigned)l1 << 16);
  }
  __syncthreads();

  // 4 Q-tiles per wave; B-frag half selected by q&1
  bf16x8 df[4];
  #pragma unroll
  for (int t = 0; t < 4; ++t)
    df[t] = *(const bf16x8*)(delta_lds + (rg*64 + t*16 + r)*16 + (q & 1)*8);

  int phi_off = (q >> 1) * 8;               // [ph ph pl pl] across k
  int key0 = (r >> 2)*8 + (r & 3);          // perm: S-tile C-layout == PV A-frag
  int key1 = key0 + 4;

  bf16x8 ones;
  #pragma unroll
  for (int i = 0; i < 8; ++i) ones[i] = (short)0x3F80;  // bf16 1.0

  f32x4 acc[4][2];                 // [tile][c-half]
  f32x4 den[4];
  f32x4 zero = {0,0,0,0};
  #pragma unroll
  for (int t = 0; t < 4; ++t) { acc[t][0] = zero; acc[t][1] = zero; den[t] = zero; }

  for (int p = 0; p < 2; ++p) {
    if (p) __syncthreads();                 // everyone done reading phase 0
    // ---- stage phi half: 1024 16B units, straight copy (R6)
    {
      const uint4* psrc = (const uint4*)(phi_s + ((size_t)b*M_ + p*512)*16);
      uint4* pdst = (uint4*)phi_lds;
      #pragma unroll
      for (int u = 0; u < 2; ++u) pdst[tid + u*512] = psrc[tid + u*512];
      // ---- stage g half: 2048 16B units into padded rows
      #pragma unroll
      for (int u = 0; u < 4; ++u) {
        int uu = tid + u*512;
        int c2 = uu >> 6, pos = uu & 63;
        *(uint4*)(g_lds + c2*520 + pos*8) =
            *(const uint4*)(g_t + ((size_t)b*C2_ + c2)*M_ + p*512 + pos*8);
      }
    }
    __syncthreads();

    // ---- K-loop on LDS only (4 chunks of 32 keys, no barriers inside)
    #pragma unroll 2
    for (int kc = 0; kc < 128; kc += 32) {
      int kl = kh*128 + kc;        // phase-local key base
      bf16x8 aphi0 = *(const bf16x8*)(phi_lds + (size_t)(kl + key0)*16 + phi_off);
      bf16x8 aphi1 = *(const bf16x8*)(phi_lds + (size_t)(kl + key1)*16 + phi_off);
      bf16x8 bg0   = *(const bf16x8*)(g_lds + r*520        + kl + q*8);
      bf16x8 bg1   = *(const bf16x8*)(g_lds + (16 + r)*520 + kl + q*8);

      #pragma unroll
      for (int t = 0; t < 4; ++t) {
        f32x4 s0 = MFMA_BF16(aphi0, df[t], zero, 0, 0, 0);
        f32x4 s1 = MFMA_BF16(aphi1, df[t], zero, 0, 0, 0);
        union { bf16x8 v; __hip_bfloat162 h[4]; } e;
        e.h[0] = __float22bfloat162_rn(make_float2(__builtin_amdgcn_exp2f(s0[0]),
                                                   __builtin_amdgcn_exp2f(s0[1])));
        e.h[1] = __float22bfloat162_rn(make_float2(__builtin_amdgcn_exp2f(s0[2]),
                                                   __builtin_amdgcn_exp2f(s0[3])));
        e.h[2] = __float22bfloat162_rn(make_float2(__builtin_amdgcn_exp2f(s1[0]),
                                                   __builtin_amdgcn_exp2f(s1[1])));
        e.h[3] = __float22bfloat162_rn(make_float2(__builtin_amdgcn_exp2f(s1[2]),
                                                   __builtin_amdgcn_exp2f(s1[3])));
        acc[t][0] = MFMA_BF16(e.v, bg0, acc[t][0], 0, 0, 0);
        acc[t][1] = MFMA_BF16(e.v, bg1, acc[t][1], 0, 0, 0);
        den[t]    = MFMA_BF16(e.v, ones, den[t], 0, 0, 0);
      }
    }
  }

  // ---- combine the four key-quarters (cmb reuses staging LDS)
  __syncthreads();                          // all waves done reading g/phi LDS
  if (kh != 0) {
    float* cb = cmb + (kh-1)*128*34;
    #pragma unroll
    for (int t = 0; t < 4; ++t) {
      #pragma unroll
      for (int reg = 0; reg < 4; ++reg) {
        int row = rg*64 + t*16 + q*4 + reg;
        cb[row*34 + r]      = acc[t][0][reg];
        cb[row*34 + 16 + r] = acc[t][1][reg];
        if (r == 0) cb[row*34 + 32] = den[t][reg];
      }
    }
  }
  __syncthreads();
  if (kh == 0) {
    #pragma unroll
    for (int t = 0; t < 4; ++t) {
      #pragma unroll
      for (int reg = 0; reg < 4; ++reg) {
        int row = rg*64 + t*16 + q*4 + reg;
        float o0 = acc[t][0][reg];
        float o1 = acc[t][1][reg];
        float dn = den[t][reg];
        #pragma unroll
        for (int pp = 0; pp < 3; ++pp) {
          const float* cb = cmb + pp*128*34;
          o0 += cb[row*34 + r];
          o1 += cb[row*34 + 16 + r];
          dn += cb[row*34 + 32];
        }
        float iv = __builtin_amdgcn_rcpf(dn);
        o_sh[row*33 + r]      = o0 * iv;
        o_sh[row*33 + 16 + r] = o1 * iv;
      }
    }
  }
  __syncthreads();

  // ---- epilogue: out[b,co,n0+rr] = gamma*(w_last[co,:].O[rr,:]+b_last[co])+x
  int rr  = tid & 127;
  int wqu = __builtin_amdgcn_readfirstlane(tid >> 7);  // 0..3, uniform
  float o_reg[32];
  #pragma unroll
  for (int c = 0; c < 32; ++c) o_reg[c] = o_sh[rr*33 + c];
  float gm = gamma[0];
  for (int i = 0; i < 16; ++i) {
    int co = wqu*16 + i;                     // uniform -> s_load weights
    const float* wl = w_last + co*32;
    float a = b_last[co];
    #pragma unroll
    for (int c = 0; c < 32; ++c) a += wl[c] * o_reg[c];
    size_t oi = ((size_t)b*C_ + co)*HW_ + (size_t)(n0 + rr);
    out[oi] = gm * a + x[oi];
  }
}

// ---------------------------------------------------------------------------
extern "C" void kernel_launch(void* const* d_in, const int* in_sizes, int n_in,
                              void* d_out, int out_size, void* d_ws, size_t ws_size,
                              hipStream_t stream) {
  const float* x       = (const float*)d_in[0];
  const float* w_delta = (const float*)d_in[1];
  const float* b_delta = (const float*)d_in[2];
  const float* w_phi   = (const float*)d_in[3];
  const float* b_phi   = (const float*)d_in[4];
  const float* w_g     = (const float*)d_in[5];
  const float* b_g     = (const float*)d_in[6];
  const float* w_last  = (const float*)d_in[7];
  const float* b_last  = (const float*)d_in[8];
  const float* gamma   = (const float*)d_in[9];
  float* out = (float*)d_out;

  unsigned short* ws = (unsigned short*)d_ws;
  unsigned short* phi_s = ws;                          // 16*1024*16 = 0.5 MB
  unsigned short* g_t   = ws + (size_t)B_*M_*16;       // 16*32*1024 = 1 MB

  hipLaunchKernelGGL(k_pre, dim3(1024), dim3(256), 0, stream,
                     x, w_phi, b_phi, w_g, b_g, phi_s, g_t);
  hipLaunchKernelGGL(k_attn, dim3(512), dim3(512), 0, stream,
                     x, w_delta, b_delta, phi_s, g_t, w_last, b_last, gamma, out);
}

// Round 11
// 114.475 us; speedup vs baseline: 1.2136x; 1.0122x over previous
//
#include <hip/hip_runtime.h>
#include <hip/hip_bf16.h>
#include <math.h>

typedef __attribute__((ext_vector_type(8))) short bf16x8;
typedef __attribute__((ext_vector_type(4))) float f32x4;

#define B_   16
#define C_   64
#define C1_  8
#define C2_  32
#define HW_  4096
#define M_   1024
#define LOG2E 1.4426950408889634f
#define MFMA_BF16 __builtin_amdgcn_mfma_f32_16x16x32_bf16

__device__ __forceinline__ unsigned short f2bf(float f) {
  union { float f; unsigned u; } v; v.f = f;
  unsigned r = (v.u + 0x7fffu + ((v.u >> 16) & 1u)) >> 16;
  return (unsigned short)r;
}
__device__ __forceinline__ float bf2f(unsigned short h) {
  union { unsigned u; float f; } v; v.u = ((unsigned)h) << 16;
  return v.f;
}

// ---------------------------------------------------------------------------
// K1: phi + g only (delta computed inside k_attn).  EXACT best-known (R6).
//   phi_s[b][m][16] : [ph(8) pl(8)] hi/lo split, batch/channel scrambled
//   g_t  [b][c2][m] : bf16 (transposed for PV B-frag reads)
// 4-way channel split over waves, shuffle-pool, scalar (s_load) weights.
// ---------------------------------------------------------------------------
__global__ __launch_bounds__(256, 4)
void k_pre(const float* __restrict__ x,
           const float* __restrict__ w_phi, const float* __restrict__ b_phi,
           const float* __restrict__ w_g,   const float* __restrict__ b_g,
           unsigned short* __restrict__ phi_s,
           unsigned short* __restrict__ g_t) {
  __shared__ float comb[2*64*41];
  int tid = threadIdx.x;

  int qt  = tid >> 6;              // channel quarter == wave index
  int sub = tid & 63;
  int id  = blockIdx.x * 64 + sub; // pixel id 0..65535
  int pix = id & 3;                // 2x2 corner (lane bits 0..1)
  int pm  = id >> 2;
  int b = pm >> 10;
  int m = pm & 1023;
  int py = 2*(m >> 5) + (pix >> 1);
  int px = 2*(m & 31) + (pix & 1);
  int n = py * 64 + px;

  int c0 = __builtin_amdgcn_readfirstlane(qt << 4);

  const float* xp = x + ((size_t)b*C_ + c0)*HW_ + n;
  float xv[16];
  #pragma unroll
  for (int i = 0; i < 16; ++i) xv[i] = xp[(size_t)i * HW_];

  float ap[8], ag[32];
  #pragma unroll
  for (int o = 0; o < 8; ++o) {
    const float* wp = w_phi + o*C_ + c0;     // uniform -> s_load
    float a = 0.f;
    #pragma unroll
    for (int i = 0; i < 16; ++i) a += xv[i]*wp[i];
    ap[o] = a;
  }
  #pragma unroll
  for (int o = 0; o < 32; ++o) {
    const float* wg = w_g + o*C_ + c0;       // uniform -> s_load
    float a = 0.f;
    #pragma unroll
    for (int i = 0; i < 16; ++i) a += xv[i]*wg[i];
    ag[o] = a;
  }

  if (qt == 1 || qt == 3) {
    float* cb = comb + (((qt >> 1)*64) + sub)*41;
    #pragma unroll
    for (int o = 0; o < 8; ++o) cb[o] = ap[o];
    #pragma unroll
    for (int o = 0; o < 32; ++o) cb[8+o] = ag[o];
  }
  __syncthreads();
  if (qt == 0 || qt == 2) {
    const float* cb = comb + (((qt >> 1)*64) + sub)*41;
    #pragma unroll
    for (int o = 0; o < 8; ++o) ap[o] += cb[o];
    #pragma unroll
    for (int o = 0; o < 32; ++o) ag[o] += cb[8+o];
  }
  __syncthreads();
  if (qt == 2) {
    float* cb = comb + sub*41;
    #pragma unroll
    for (int o = 0; o < 8; ++o) cb[o] = ap[o];
    #pragma unroll
    for (int o = 0; o < 32; ++o) cb[8+o] = ag[o];
  }
  __syncthreads();
  if (qt == 0) {
    const float* cb = comb + sub*41;
    #pragma unroll
    for (int o = 0; o < 8; ++o) ap[o] += cb[o];
    #pragma unroll
    for (int o = 0; o < 32; ++o) ag[o] += cb[8+o];

    #pragma unroll
    for (int o = 0; o < 8; ++o) {
      float v = ap[o];
      v = fmaxf(v, __shfl_xor(v, 1));
      v = fmaxf(v, __shfl_xor(v, 2));
      ap[o] = v;
    }
    #pragma unroll
    for (int o = 0; o < 32; ++o) {
      float v = ag[o];
      v = fmaxf(v, __shfl_xor(v, 1));
      v = fmaxf(v, __shfl_xor(v, 2));
      ag[o] = v;
    }

    if ((sub & 3) == 0) {
      #pragma unroll
      for (int cp = 0; cp < 8; ++cp) {
        int f = cp*16 + b;
        float v = ap[cp] + b_phi[cp];
        unsigned short hi = f2bf(v);
        unsigned short* pr = phi_s + ((size_t)(f >> 3)*M_ + m)*16;
        pr[f & 7]       = hi;
        pr[8 + (f & 7)] = f2bf(v - bf2f(hi));
      }
      #pragma unroll
      for (int o = 0; o < 32; ++o)
        g_t[((size_t)b*C2_ + o)*M_ + m] = f2bf(ag[o] + b_g[o]);
    }
  }
}

// ---------------------------------------------------------------------------
// K2: delta conv (in-block) + MFMA flash attention (no-max softmax) +
// fused last conv + residual.  EXACT best-known (R6, 114.70 us).
// Block = 512 thr (8 waves = 4 row-groups x 2 key-halves), 128 Q-rows,
// 512 blocks. phi+g staged through LDS in two key-phases; K-loop reads
// only LDS. delta in its own 4 KB LDS region.
// ---------------------------------------------------------------------------
__global__ __launch_bounds__(512, 4)
void k_attn(const float* __restrict__ x,
            const float* __restrict__ w_delta,
            const float* __restrict__ b_delta,
            const unsigned short* __restrict__ phi_s,
            const unsigned short* __restrict__ g_t,
            const float* __restrict__ w_last,
            const float* __restrict__ b_last,
            const float* __restrict__ gamma,
            float* __restrict__ out) {
  __shared__ __align__(16) unsigned char lds_raw[50176];
  __shared__ __align__(8)  unsigned short delta_lds[128*16];   // [row][dh8 dl8]
  unsigned short* phi_lds = (unsigned short*)lds_raw;          // 512*16*2  = 16384 B
  unsigned short* g_lds   = (unsigned short*)(lds_raw + 16384);// 32*520*2  = 33280 B
  float* o_sh = (float*)lds_raw;                               // 128*33*4  = 16896 B (reuse)
  float* cmb  = (float*)(lds_raw + 16896);                     // 128*34*4  = 17408 B (reuse)

  int tid  = threadIdx.x;
  int lane = tid & 63;
  int wv   = tid >> 6;             // 0..7
  int rg   = wv & 3;               // row-group: rows rg*32 .. rg*32+31
  int kh   = wv >> 2;              // key half within phase (256 keys)
  int r    = lane & 15;
  int q    = lane >> 4;
  int bx = blockIdx.x;             // 0..511
  int b  = bx >> 5;
  int n0 = (bx & 31) * 128;

  // ---- delta preamble: 4 threads/row x 2 channels, scalar weights
  {
    int row  = tid & 127;
    int cp2  = __builtin_amdgcn_readfirstlane(tid >> 7);  // 0..3, wave-uniform
    const float* wd0 = w_delta + (2*cp2)   * C_;
    const float* wd1 = w_delta + (2*cp2+1) * C_;
    const float* xr  = x + (size_t)b*C_*HW_ + n0 + row;
    float a0 = 0.f, a1 = 0.f;
    #pragma unroll
    for (int c = 0; c < C_; ++c) {
      float v = xr[(size_t)c * HW_];
      a0 += v * wd0[c];
      a1 += v * wd1[c];
    }
    a0 = (a0 + b_delta[2*cp2])   * LOG2E;
    a1 = (a1 + b_delta[2*cp2+1]) * LOG2E;
    unsigned short h0 = f2bf(a0), h1 = f2bf(a1);
    unsigned short l0 = f2bf(a0 - bf2f(h0)), l1 = f2bf(a1 - bf2f(h1));
    *(unsigned*)(delta_lds + row*16 + 2*cp2)     = (unsigned)h0 | ((unsigned)h1 << 16);
    *(unsigned*)(delta_lds + row*16 + 8 + 2*cp2) = (unsigned)l0 | ((unsigned)l1 << 16);
  }
  __syncthreads();

  // 2 Q-tiles per wave; B-frag half selected by q&1
  bf16x8 df[2];
  #pragma unroll
  for (int t = 0; t < 2; ++t)
    df[t] = *(const bf16x8*)(delta_lds + (rg*32 + t*16 + r)*16 + (q & 1)*8);

  int phi_off = (q >> 1) * 8;               // [ph ph pl pl] across k
  int key0 = (r >> 2)*8 + (r & 3);          // perm: S-tile C-layout == PV A-frag
  int key1 = key0 + 4;

  bf16x8 ones;
  #pragma unroll
  for (int i = 0; i < 8; ++i) ones[i] = (short)0x3F80;  // bf16 1.0

  f32x4 acc[2][2];                 // [tile][c-half]
  f32x4 den[2];
  f32x4 zero = {0,0,0,0};
  #pragma unroll
  for (int t = 0; t < 2; ++t) { acc[t][0] = zero; acc[t][1] = zero; den[t] = zero; }

  for (int p = 0; p < 2; ++p) {
    if (p) __syncthreads();                 // everyone done reading phase 0
    // ---- stage phi half: 1024 16B units, straight copy
    {
      const uint4* psrc = (const uint4*)(phi_s + ((size_t)b*M_ + p*512)*16);
      uint4* pdst = (uint4*)phi_lds;
      #pragma unroll
      for (int u = 0; u < 2; ++u) pdst[tid + u*512] = psrc[tid + u*512];
      // ---- stage g half: 2048 16B units into padded rows
      #pragma unroll
      for (int u = 0; u < 4; ++u) {
        int uu = tid + u*512;
        int c2 = uu >> 6, pos = uu & 63;
        *(uint4*)(g_lds + c2*520 + pos*8) =
            *(const uint4*)(g_t + ((size_t)b*C2_ + c2)*M_ + p*512 + pos*8);
      }
    }
    __syncthreads();

    // ---- K-loop on LDS only (no barriers inside)
    #pragma unroll 2
    for (int kc = 0; kc < 256; kc += 32) {
      int kl = kh*256 + kc;        // phase-local key base
      bf16x8 aphi0 = *(const bf16x8*)(phi_lds + (size_t)(kl + key0)*16 + phi_off);
      bf16x8 aphi1 = *(const bf16x8*)(phi_lds + (size_t)(kl + key1)*16 + phi_off);
      bf16x8 bg0   = *(const bf16x8*)(g_lds + r*520        + kl + q*8);
      bf16x8 bg1   = *(const bf16x8*)(g_lds + (16 + r)*520 + kl + q*8);

      #pragma unroll
      for (int t = 0; t < 2; ++t) {
        f32x4 s0 = MFMA_BF16(aphi0, df[t], zero, 0, 0, 0);
        f32x4 s1 = MFMA_BF16(aphi1, df[t], zero, 0, 0, 0);
        union { bf16x8 v; __hip_bfloat162 h[4]; } e;
        e.h[0] = __float22bfloat162_rn(make_float2(__builtin_amdgcn_exp2f(s0[0]),
                                                   __builtin_amdgcn_exp2f(s0[1])));
        e.h[1] = __float22bfloat162_rn(make_float2(__builtin_amdgcn_exp2f(s0[2]),
                                                   __builtin_amdgcn_exp2f(s0[3])));
        e.h[2] = __float22bfloat162_rn(make_float2(__builtin_amdgcn_exp2f(s1[0]),
                                                   __builtin_amdgcn_exp2f(s1[1])));
        e.h[3] = __float22bfloat162_rn(make_float2(__builtin_amdgcn_exp2f(s1[2]),
                                                   __builtin_amdgcn_exp2f(s1[3])));
        acc[t][0] = MFMA_BF16(e.v, bg0, acc[t][0], 0, 0, 0);
        acc[t][1] = MFMA_BF16(e.v, bg1, acc[t][1], 0, 0, 0);
        den[t]    = MFMA_BF16(e.v, ones, den[t], 0, 0, 0);
      }
    }
  }

  // ---- combine the two key-halves (cmb reuses staging LDS)
  __syncthreads();                          // all waves done reading g/phi LDS
  if (kh == 1) {
    #pragma unroll
    for (int t = 0; t < 2; ++t) {
      #pragma unroll
      for (int reg = 0; reg < 4; ++reg) {
        int row = rg*32 + t*16 + q*4 + reg;
        cmb[row*34 + r]      = acc[t][0][reg];
        cmb[row*34 + 16 + r] = acc[t][1][reg];
        if (r == 0) cmb[row*34 + 32] = den[t][reg];
      }
    }
  }
  __syncthreads();
  if (kh == 0) {
    #pragma unroll
    for (int t = 0; t < 2; ++t) {
      #pragma unroll
      for (int reg = 0; reg < 4; ++reg) {
        int row = rg*32 + t*16 + q*4 + reg;
        float o0 = acc[t][0][reg] + cmb[row*34 + r];
        float o1 = acc[t][1][reg] + cmb[row*34 + 16 + r];
        float dn = den[t][reg]    + cmb[row*34 + 32];
        float iv = __builtin_amdgcn_rcpf(dn);
        o_sh[row*33 + r]      = o0 * iv;
        o_sh[row*33 + 16 + r] = o1 * iv;
      }
    }
  }
  __syncthreads();

  // ---- epilogue: out[b,co,n0+rr] = gamma*(w_last[co,:].O[rr,:]+b_last[co])+x
  int rr  = tid & 127;
  int wqu = __builtin_amdgcn_readfirstlane(tid >> 7);  // 0..3, uniform
  float o_reg[32];
  #pragma unroll
  for (int c = 0; c < 32; ++c) o_reg[c] = o_sh[rr*33 + c];
  float gm = gamma[0];
  for (int i = 0; i < 16; ++i) {
    int co = wqu*16 + i;                     // uniform -> s_load weights
    const float* wl = w_last + co*32;
    float a = b_last[co];
    #pragma unroll
    for (int c = 0; c < 32; ++c) a += wl[c] * o_reg[c];
    size_t oi = ((size_t)b*C_ + co)*HW_ + (size_t)(n0 + rr);
    out[oi] = gm * a + x[oi];
  }
}

// ---------------------------------------------------------------------------
extern "C" void kernel_launch(void* const* d_in, const int* in_sizes, int n_in,
                              void* d_out, int out_size, void* d_ws, size_t ws_size,
                              hipStream_t stream) {
  const float* x       = (const float*)d_in[0];
  const float* w_delta = (const float*)d_in[1];
  const float* b_delta = (const float*)d_in[2];
  const float* w_phi   = (const float*)d_in[3];
  const float* b_phi   = (const float*)d_in[4];
  const float* w_g     = (const float*)d_in[5];
  const float* b_g     = (const float*)d_in[6];
  const float* w_last  = (const float*)d_in[7];
  const float* b_last  = (const float*)d_in[8];
  const float* gamma   = (const float*)d_in[9];
  float* out = (float*)d_out;

  unsigned short* ws = (unsigned short*)d_ws;
  unsigned short* phi_s = ws;                          // 16*1024*16 = 0.5 MB
  unsigned short* g_t   = ws + (size_t)B_*M_*16;       // 16*32*1024 = 1 MB

  hipLaunchKernelGGL(k_pre, dim3(1024), dim3(256), 0, stream,
                     x, w_phi, b_phi, w_g, b_g, phi_s, g_t);
  hipLaunchKernelGGL(k_attn, dim3(512), dim3(512), 0, stream,
                     x, w_delta, b_delta, phi_s, g_t, w_last, b_last, gamma, out);
}